// Round 2
// 522.087 us; speedup vs baseline: 1.3052x; 1.3052x over previous
//
#include <hip/hip_runtime.h>

#define NEGV (-10000.0f)

constexpr int B_ = 512;
constexpr int S_ = 1024;
constexpr int NL_ = 49;
constexpr int L_ = 51;   // NL + 2; start = 49, end = 50

__device__ __forceinline__ float readlane_f(float v, int l) {
    return __int_as_float(__builtin_amdgcn_readlane(__float_as_int(v), l));
}

// v = max(v, dpp_move(v, CTRL)); CTRL must be a compile-time constant.
// bound_ctrl=false + old=v: lanes with no valid source keep v (identity for max).
template <int CTRL>
__device__ __forceinline__ float dpp_max_step(float v) {
    int sh = __builtin_amdgcn_update_dpp(__float_as_int(v), __float_as_int(v),
                                         CTRL, 0xf, 0xf, false);
    return fmaxf(v, __int_as_float(sh));
}

// Full 64-lane max, returned as a wave-uniform scalar (SGPR).
// Classic gfx9 sequence: row_shr 1/2/4/8 then row_bcast:15 / row_bcast:31 -> lane 63.
__device__ __forceinline__ float wave_max_sgpr(float v) {
    v = dpp_max_step<0x111>(v);  // row_shr:1
    v = dpp_max_step<0x112>(v);  // row_shr:2
    v = dpp_max_step<0x114>(v);  // row_shr:4
    v = dpp_max_step<0x118>(v);  // row_shr:8
    v = dpp_max_step<0x142>(v);  // row_bcast:15
    v = dpp_max_step<0x143>(v);  // row_bcast:31
    return readlane_f(v, 63);
}

__global__ __launch_bounds__(64, 1) void crf_fwd(
    const float* __restrict__ logits,      // (B, S, NL)
    const float* __restrict__ transition,  // (L, L)
    const int*   __restrict__ labels,      // (B, S)
    const int*   __restrict__ lens,        // (B,)
    float*       __restrict__ out)         // (B,)
{
    const int b    = blockIdx.x;
    const int lane = threadIdx.x;
    const int len  = __builtin_amdgcn_readfirstlane(lens[b]);  // wave-uniform, >= 1

    const float* __restrict__ lg  = logits + (size_t)b * (S_ * NL_);
    const int*   __restrict__ lab = labels + (size_t)b * S_;

    // ---- per-lane transition row (rows 0..48 only — start row is dead after t=0,
    //      end column is identically 0 in exp-space), exponentiated ----
    float Erow[NL_];
    float Tend, estart;
    {
        const bool st = (lane < NL_);
        const float* trow = transition + ((lane < L_) ? lane : 0) * L_;
        #pragma unroll
        for (int j = 0; j < NL_; ++j) {
            float tv = trow[j];
            Erow[j] = st ? __expf(tv) : 0.0f;
        }
        estart = __expf(trow[NL_]);                    // exp(T[lane][start])
        Tend   = (lane < L_) ? transition[(L_ - 1) * L_ + lane] : NEGV;
    }

    // ---- gold score: lane-parallel over time ----
    float g = 0.0f;
    for (int t = lane; t < S_; t += 64) {
        if (t < len) {
            int c = lab[t];
            int p = (t == 0) ? (L_ - 2) : lab[t - 1];
            g += lg[t * NL_ + c] + transition[c * L_ + p];
            if (t == len - 1) g += transition[(L_ - 1) * L_ + c];  // end transition
        }
    }
    #pragma unroll
    for (int o = 32; o >= 1; o >>= 1) g += __shfl_xor(g, o, 64);

    // ---- forward scan ----
    // t = 0 analytically: alpha_i = lg[0][i] + log(exp(T[i][start]))
    // (log(exp(.)) kept for bit-parity with the previous kernel's step-0 rounding)
    float alpha;
    {
        float lg0 = (lane < NL_) ? lg[lane] : NEGV;
        alpha = (lane < NL_) ? (lg0 + __logf(estart)) : NEGV;
    }
    float M = 0.0f;   // max of alpha BEFORE step 0 (start vector) = 0; stale-by-1

    auto loadlg = [&](int t) -> float {
        float v = NEGV;
        if (lane < NL_) v = lg[t * NL_ + lane];
        return v;
    };

    float buf0 = loadlg(1);
    float buf1 = loadlg(2);
    float buf2 = loadlg(3);
    float buf3 = loadlg(4);

    auto substep = [&](float cur, int t) {
        float p  = __expf(alpha - M);       // bounded: alpha - stale_max small
        float Mn = wave_max_sgpr(alpha);    // for NEXT step — VALU pipe, off crit path
        // y_i = sum_{j<49} E[i][j] * p_j   (j=49 dead after t=0, j=50 has E==0)
        float y0 = 0.f, y1 = 0.f, y2 = 0.f, y3 = 0.f;
        #pragma unroll
        for (int j = 0; j < 48; j += 4) {
            y0 = fmaf(readlane_f(p, j + 0), Erow[j + 0], y0);
            y1 = fmaf(readlane_f(p, j + 1), Erow[j + 1], y1);
            y2 = fmaf(readlane_f(p, j + 2), Erow[j + 2], y2);
            y3 = fmaf(readlane_f(p, j + 3), Erow[j + 3], y3);
        }
        y0 = fmaf(readlane_f(p, 48), Erow[48], y0);
        float y = (y0 + y1) + (y2 + y3);
        float anew = cur + M + __logf(y);
        if (t < len && lane < NL_) alpha = anew;   // uniform t<len; cndmask on lane
        M = Mn;
    };

    const int tEnd = 1 + (((len - 1) + 3) & ~3);   // steps t = 1 .. len-1, padded to 4
    for (int t = 1; t < tEnd; t += 4) {
        int t4 = t + 4; t4 = (t4 < S_) ? t4 : (S_ - 1);
        int t5 = t + 5; t5 = (t5 < S_) ? t5 : (S_ - 1);
        int t6 = t + 6; t6 = (t6 < S_) ? t6 : (S_ - 1);
        int t7 = t + 7; t7 = (t7 < S_) ? t7 : (S_ - 1);
        substep(buf0, t + 0); buf0 = loadlg(t4);
        substep(buf1, t + 1); buf1 = loadlg(t5);
        substep(buf2, t + 2); buf2 = loadlg(t6);
        substep(buf3, t + 3); buf3 = loadlg(t7);
    }

    // ---- norm = LSE_i(alpha_i + T[end, i]) ----
    float x = (lane < L_) ? (alpha + Tend) : NEGV;
    float mx = x;
    #pragma unroll
    for (int o = 32; o >= 1; o >>= 1) mx = fmaxf(mx, __shfl_xor(mx, o, 64));
    float e = __expf(x - mx);
    #pragma unroll
    for (int o = 32; o >= 1; o >>= 1) e += __shfl_xor(e, o, 64);
    float norm = mx + __logf(e);

    if (lane == 0) out[b] = g - norm;
}

extern "C" void kernel_launch(void* const* d_in, const int* in_sizes, int n_in,
                              void* d_out, int out_size, void* d_ws, size_t ws_size,
                              hipStream_t stream) {
    const float* logits     = (const float*)d_in[0];
    const float* transition = (const float*)d_in[1];
    const int*   labels     = (const int*)d_in[2];
    const int*   lens       = (const int*)d_in[3];
    float*       out        = (float*)d_out;
    crf_fwd<<<dim3(B_), dim3(64), 0, stream>>>(logits, transition, labels, lens, out);
}